// Round 1
// baseline (672.063 us; speedup 1.0000x reference)
//
#include <hip/hip_runtime.h>
#include <hip/hip_bf16.h>
#include <math.h>

// Problem constants
#define BSZ   2
#define NTOK  1024          // 32*32
#define CDIM  512
#define SENC  77
#define SKV   1101          // 77 + 1024
#define ENCD  768
#define NHEAD 64            // heads of dim 8 (faithful to source)
#define DHEAD 8
#define GN_G  32

// ---------------------------------------------------------------- reductions
__device__ __forceinline__ float block_reduce_sum(float v) {
    // 256 threads = 4 waves of 64
    #pragma unroll
    for (int off = 32; off > 0; off >>= 1) v += __shfl_down(v, off, 64);
    __shared__ float tmp[4];
    int lane = threadIdx.x & 63, wid = threadIdx.x >> 6;
    if (lane == 0) tmp[wid] = v;
    __syncthreads();
    if (wid == 0) {
        float r = (lane < 4) ? tmp[lane] : 0.f;
        r += __shfl_down(r, 2, 64);
        r += __shfl_down(r, 1, 64);
        if (lane == 0) tmp[0] = r;
    }
    __syncthreads();
    float out = tmp[0];
    __syncthreads();   // safe reuse across calls
    return out;
}

// ---------------------------------------------------------------- layernorm (enc)
// grid = B*SENC blocks, 256 threads; row of 768
__global__ __launch_bounds__(256) void layernorm_kernel(
        const float* __restrict__ x, const float* __restrict__ sc,
        const float* __restrict__ bi, float* __restrict__ out) {
    int row = blockIdx.x;
    const float* xp = x + (size_t)row * ENCD;
    float* op = out + (size_t)row * ENCD;
    int t = threadIdx.x;
    float v0 = xp[t], v1 = xp[t + 256], v2 = xp[t + 512];
    float mu = block_reduce_sum(v0 + v1 + v2) * (1.f / ENCD);
    float d0 = v0 - mu, d1 = v1 - mu, d2 = v2 - mu;
    float var = block_reduce_sum(d0 * d0 + d1 * d1 + d2 * d2) * (1.f / ENCD);
    float rstd = rsqrtf(var + 1e-5f);
    op[t]       = d0 * rstd * sc[t]       + bi[t];
    op[t + 256] = d1 * rstd * sc[t + 256] + bi[t + 256];
    op[t + 512] = d2 * rstd * sc[t + 512] + bi[t + 512];
}

// ---------------------------------------------------------------- groupnorm (hs)
// grid = B*GN_G blocks (64), 256 threads. Stats over (N=1024, 16 channels).
__global__ __launch_bounds__(256) void groupnorm_kernel(
        const float* __restrict__ x, const float* __restrict__ sc,
        const float* __restrict__ bi, float* __restrict__ out) {
    int b = blockIdx.x >> 5, g = blockIdx.x & 31;
    const float* xp = x + (size_t)b * NTOK * CDIM + g * 16;
    float* op = out + (size_t)b * NTOK * CDIM + g * 16;
    int t = threadIdx.x;

    float s = 0.f;
    for (int idx = t; idx < 4096; idx += 256) {        // 4096 float4 = 16384 floats
        int n = idx >> 2, q = idx & 3;
        float4 v = *(const float4*)(xp + n * CDIM + q * 4);
        s += (v.x + v.y) + (v.z + v.w);
    }
    float mu = block_reduce_sum(s) * (1.f / 16384.f);

    float vs = 0.f;
    for (int idx = t; idx < 4096; idx += 256) {
        int n = idx >> 2, q = idx & 3;
        float4 v = *(const float4*)(xp + n * CDIM + q * 4);
        float dx = v.x - mu, dy = v.y - mu, dz = v.z - mu, dw = v.w - mu;
        vs += (dx * dx + dy * dy) + (dz * dz + dw * dw);
    }
    float var = block_reduce_sum(vs) * (1.f / 16384.f);
    float rstd = rsqrtf(var + 1e-5f);

    for (int idx = t; idx < 4096; idx += 256) {
        int n = idx >> 2, q = idx & 3;
        float4 v = *(const float4*)(xp + n * CDIM + q * 4);
        float4 s4 = *(const float4*)(sc + g * 16 + q * 4);
        float4 b4 = *(const float4*)(bi + g * 16 + q * 4);
        float4 o;
        o.x = (v.x - mu) * rstd * s4.x + b4.x;
        o.y = (v.y - mu) * rstd * s4.y + b4.y;
        o.z = (v.z - mu) * rstd * s4.z + b4.z;
        o.w = (v.w - mu) * rstd * s4.w + b4.w;
        *(float4*)(op + n * CDIM + q * 4) = o;
    }
}

// ---------------------------------------------------------------- fp32 tiled GEMM
// out[M,Ncol] = A[M,K] @ W[K,Ncol] + bias.  64x64 tile, BK=16, 256 thr, 4x4 micro.
__global__ __launch_bounds__(256) void gemm_bias(
        const float* __restrict__ A, const float* __restrict__ W,
        const float* __restrict__ bias, float* __restrict__ out,
        int M, int K, int Ncol) {
    __shared__ float As[16][65];
    __shared__ float Bs[16][65];
    int tid = threadIdx.x;
    int c0 = blockIdx.x * 64, m0 = blockIdx.y * 64;
    int tx = tid & 15, ty = tid >> 4;
    float acc[4][4] = {};

    for (int k0 = 0; k0 < K; k0 += 16) {
        #pragma unroll
        for (int i = 0; i < 4; ++i) {
            int flat = tid + i * 256;          // 0..1023
            int r = flat >> 4, kk = flat & 15;
            int row = m0 + r;
            As[kk][r] = (row < M) ? A[(size_t)row * K + k0 + kk] : 0.f;
        }
        #pragma unroll
        for (int i = 0; i < 4; ++i) {
            int flat = tid + i * 256;
            int kk = flat >> 6, c = flat & 63;
            Bs[kk][c] = W[(size_t)(k0 + kk) * Ncol + c0 + c];
        }
        __syncthreads();
        #pragma unroll
        for (int kk = 0; kk < 16; ++kk) {
            float a[4], bb[4];
            #pragma unroll
            for (int i = 0; i < 4; ++i) a[i] = As[kk][ty * 4 + i];
            #pragma unroll
            for (int j = 0; j < 4; ++j) bb[j] = Bs[kk][tx * 4 + j];
            #pragma unroll
            for (int i = 0; i < 4; ++i)
                #pragma unroll
                for (int j = 0; j < 4; ++j)
                    acc[i][j] = fmaf(a[i], bb[j], acc[i][j]);
        }
        __syncthreads();
    }
    #pragma unroll
    for (int i = 0; i < 4; ++i) {
        int row = m0 + ty * 4 + i;
        if (row < M) {
            #pragma unroll
            for (int j = 0; j < 4; ++j) {
                int c = c0 + tx * 4 + j;
                out[(size_t)row * Ncol + c] = acc[i][j] + bias[c];
            }
        }
    }
}

// ------------------------------------------- out-proj GEMM + bias + residual,
// writes transposed layout out[(b*C + c)*N + n] coalesced via LDS transpose.
__global__ __launch_bounds__(256) void gemm_out(
        const float* __restrict__ A, const float* __restrict__ W,
        const float* __restrict__ bias, const float* __restrict__ xin,
        float* __restrict__ out) {
    const int K = CDIM, Ncol = CDIM;
    __shared__ float As[16][65];
    __shared__ float Bs[16][65];
    __shared__ float T[64][65];
    int tid = threadIdx.x;
    int c0 = blockIdx.x * 64, m0 = blockIdx.y * 64;
    int tx = tid & 15, ty = tid >> 4;
    float acc[4][4] = {};

    for (int k0 = 0; k0 < K; k0 += 16) {
        #pragma unroll
        for (int i = 0; i < 4; ++i) {
            int flat = tid + i * 256;
            int r = flat >> 4, kk = flat & 15;
            As[kk][r] = A[(size_t)(m0 + r) * K + k0 + kk];
        }
        #pragma unroll
        for (int i = 0; i < 4; ++i) {
            int flat = tid + i * 256;
            int kk = flat >> 6, c = flat & 63;
            Bs[kk][c] = W[(size_t)(k0 + kk) * Ncol + c0 + c];
        }
        __syncthreads();
        #pragma unroll
        for (int kk = 0; kk < 16; ++kk) {
            float a[4], bb[4];
            #pragma unroll
            for (int i = 0; i < 4; ++i) a[i] = As[kk][ty * 4 + i];
            #pragma unroll
            for (int j = 0; j < 4; ++j) bb[j] = Bs[kk][tx * 4 + j];
            #pragma unroll
            for (int i = 0; i < 4; ++i)
                #pragma unroll
                for (int j = 0; j < 4; ++j)
                    acc[i][j] = fmaf(a[i], bb[j], acc[i][j]);
        }
        __syncthreads();
    }
    // bias + residual (coalesced read of xin in row-major), stage to LDS
    #pragma unroll
    for (int i = 0; i < 4; ++i) {
        int row = m0 + ty * 4 + i;
        #pragma unroll
        for (int j = 0; j < 4; ++j) {
            int c = c0 + tx * 4 + j;
            T[ty * 4 + i][tx * 4 + j] = acc[i][j] + bias[c] + xin[(size_t)row * CDIM + c];
        }
    }
    __syncthreads();
    int bb_ = m0 >> 10;           // batch (tile never straddles batch: 64 | 1024)
    int nbase = m0 & 1023;
    #pragma unroll
    for (int i = 0; i < 16; ++i) {
        int flat = tid + i * 256;
        int cc = flat >> 6, nn = flat & 63;
        out[(size_t)(bb_ * CDIM + c0 + cc) * NTOK + nbase + nn] = T[nn][cc];
    }
}

// ---------------------------------------------------------------- attention
// grid = (B*NHEAD)*4 blocks (512), 256 threads; 1 thread = 1 query.
// KV tiled 256-wide into LDS; branchless online softmax; d=8 in registers.
__global__ __launch_bounds__(256) void attn_kernel(
        const float* __restrict__ Q, const float* __restrict__ Kself,
        const float* __restrict__ Vself, const float* __restrict__ Kenc,
        const float* __restrict__ Venc, float* __restrict__ O) {
    __shared__ float Ks[256][8];
    __shared__ float Vs[256][8];
    int bh = blockIdx.x >> 2, qt = blockIdx.x & 3;
    int b = bh >> 6, h = bh & 63;
    int tid = threadIdx.x;
    int n = qt * 256 + tid;                 // query index, always < 1024
    int coff = h * DHEAD;

    const float* qp = Q + ((size_t)(b * NTOK + n) * CDIM + coff);
    float4 q0 = *(const float4*)qp;
    float4 q1 = *(const float4*)(qp + 4);
    const float scale = 0.3535533905932738f;   // 1/sqrt(8)
    q0.x *= scale; q0.y *= scale; q0.z *= scale; q0.w *= scale;
    q1.x *= scale; q1.y *= scale; q1.z *= scale; q1.w *= scale;

    float m = -INFINITY, l = 0.f;
    float a0 = 0, a1 = 0, a2 = 0, a3 = 0, a4 = 0, a5 = 0, a6 = 0, a7 = 0;

    for (int j0 = 0; j0 < SKV; j0 += 256) {
        int cnt = SKV - j0; if (cnt > 256) cnt = 256;
        int j = j0 + tid;
        if (tid < cnt) {
            const float* kp;
            const float* vp;
            if (j < SENC) {
                kp = Kenc + ((size_t)(b * SENC + j) * CDIM + coff);
                vp = Venc + ((size_t)(b * SENC + j) * CDIM + coff);
            } else {
                kp = Kself + ((size_t)(b * NTOK + (j - SENC)) * CDIM + coff);
                vp = Vself + ((size_t)(b * NTOK + (j - SENC)) * CDIM + coff);
            }
            *(float4*)(&Ks[tid][0]) = *(const float4*)kp;
            *(float4*)(&Ks[tid][4]) = *(const float4*)(kp + 4);
            *(float4*)(&Vs[tid][0]) = *(const float4*)vp;
            *(float4*)(&Vs[tid][4]) = *(const float4*)(vp + 4);
        }
        __syncthreads();
        for (int jj = 0; jj < cnt; ++jj) {
            float4 k0 = *(const float4*)(&Ks[jj][0]);
            float4 k1 = *(const float4*)(&Ks[jj][4]);
            float s = q0.x * k0.x + q0.y * k0.y + q0.z * k0.z + q0.w * k0.w
                    + q1.x * k1.x + q1.y * k1.y + q1.z * k1.z + q1.w * k1.w;
            float mn = fmaxf(m, s);
            float corr = __expf(m - mn);
            float p = __expf(s - mn);
            l = l * corr + p;
            float4 v0 = *(const float4*)(&Vs[jj][0]);
            float4 v1 = *(const float4*)(&Vs[jj][4]);
            a0 = a0 * corr + p * v0.x;  a1 = a1 * corr + p * v0.y;
            a2 = a2 * corr + p * v0.z;  a3 = a3 * corr + p * v0.w;
            a4 = a4 * corr + p * v1.x;  a5 = a5 * corr + p * v1.y;
            a6 = a6 * corr + p * v1.z;  a7 = a7 * corr + p * v1.w;
            m = mn;
        }
        __syncthreads();
    }
    float inv = 1.f / l;
    float* op = O + ((size_t)(b * NTOK + n) * CDIM + coff);
    float4 o0 = make_float4(a0 * inv, a1 * inv, a2 * inv, a3 * inv);
    float4 o1 = make_float4(a4 * inv, a5 * inv, a6 * inv, a7 * inv);
    *(float4*)op = o0;
    *(float4*)(op + 4) = o1;
}

// ---------------------------------------------------------------- launcher
extern "C" void kernel_launch(void* const* d_in, const int* in_sizes, int n_in,
                              void* d_out, int out_size, void* d_ws, size_t ws_size,
                              hipStream_t stream) {
    const float* x    = (const float*)d_in[0];   // hidden_states [2,32,32,512]
    const float* enc  = (const float*)d_in[1];   // encoder_hidden_states [2,77,768]
    const float* gn_s = (const float*)d_in[2];
    const float* gn_b = (const float*)d_in[3];
    const float* ln_s = (const float*)d_in[4];
    const float* ln_b = (const float*)d_in[5];
    const float* Wq  = (const float*)d_in[6];   const float* bq  = (const float*)d_in[7];
    const float* Wk  = (const float*)d_in[8];   const float* bk  = (const float*)d_in[9];
    const float* Wv  = (const float*)d_in[10];  const float* bv  = (const float*)d_in[11];
    const float* Wak = (const float*)d_in[12];  const float* bak = (const float*)d_in[13];
    const float* Wav = (const float*)d_in[14];  const float* bav = (const float*)d_in[15];
    const float* Wo  = (const float*)d_in[16];  const float* bo  = (const float*)d_in[17];
    float* out = (float*)d_out;

    // workspace carve-up (floats)
    float* ws    = (float*)d_ws;
    float* enc_n = ws;                       // 2*77*768   = 118272
    float* hs_n  = enc_n + 118272;           // 2*1024*512 = 1048576
    float* Qm    = hs_n  + 1048576;
    float* Km    = Qm    + 1048576;
    float* Vm    = Km    + 1048576;
    float* KencM = Vm    + 1048576;          // 2*77*512 = 78848
    float* VencM = KencM + 78848;
    float* AO    = VencM + 78848;            // 1048576

    layernorm_kernel<<<BSZ * SENC, 256, 0, stream>>>(enc, ln_s, ln_b, enc_n);
    groupnorm_kernel<<<BSZ * GN_G, 256, 0, stream>>>(x, gn_s, gn_b, hs_n);

    dim3 g1(CDIM / 64, (BSZ * NTOK) / 64);       // (8, 32)
    gemm_bias<<<g1, 256, 0, stream>>>(hs_n, Wq, bq, Qm, BSZ * NTOK, CDIM, CDIM);
    gemm_bias<<<g1, 256, 0, stream>>>(hs_n, Wk, bk, Km, BSZ * NTOK, CDIM, CDIM);
    gemm_bias<<<g1, 256, 0, stream>>>(hs_n, Wv, bv, Vm, BSZ * NTOK, CDIM, CDIM);

    dim3 g2(CDIM / 64, (BSZ * SENC + 63) / 64);  // (8, 3)
    gemm_bias<<<g2, 256, 0, stream>>>(enc_n, Wak, bak, KencM, BSZ * SENC, ENCD, CDIM);
    gemm_bias<<<g2, 256, 0, stream>>>(enc_n, Wav, bav, VencM, BSZ * SENC, ENCD, CDIM);

    attn_kernel<<<BSZ * NHEAD * 4, 256, 0, stream>>>(Qm, Km, Vm, KencM, VencM, AO);

    gemm_out<<<g1, 256, 0, stream>>>(AO, Wo, bo, x, out);

    (void)in_sizes; (void)n_in; (void)out_size; (void)ws_size;
}

// Round 3
// 336.534 us; speedup vs baseline: 1.9970x; 1.9970x over previous
//
#include <hip/hip_runtime.h>
#include <math.h>

// Problem constants
#define BSZ   2
#define NTOK  1024          // 32*32
#define CDIM  512
#define SENC  77
#define SKV   1101          // 77 + 1024
#define ENCD  768
#define NHEAD 64
#define DHEAD 8

typedef short short8 __attribute__((ext_vector_type(8)));
typedef float floatx4 __attribute__((ext_vector_type(4)));

__device__ __forceinline__ unsigned short f2bf(float f) {
    union { float f; unsigned int u; } v; v.f = f;
    unsigned int r = v.u + 0x7FFF + ((v.u >> 16) & 1);   // RNE
    return (unsigned short)(r >> 16);
}

// C-style casts: clang only allows addrspacecast via C-style, not static/reinterpret_cast
__device__ __forceinline__ void gld16(const void* g, void* l) {
    __builtin_amdgcn_global_load_lds(
        (const __attribute__((address_space(1))) unsigned int*)g,
        (__attribute__((address_space(3))) unsigned int*)l,
        16, 0, 0);
}

// ---------------------------------------------------------------- reductions
__device__ __forceinline__ float block_reduce_sum(float v) {
    #pragma unroll
    for (int off = 32; off > 0; off >>= 1) v += __shfl_down(v, off, 64);
    __shared__ float tmp[4];
    int lane = threadIdx.x & 63, wid = threadIdx.x >> 6;
    if (lane == 0) tmp[wid] = v;
    __syncthreads();
    if (wid == 0) {
        float r = (lane < 4) ? tmp[lane] : 0.f;
        r += __shfl_down(r, 2, 64);
        r += __shfl_down(r, 1, 64);
        if (lane == 0) tmp[0] = r;
    }
    __syncthreads();
    float out = tmp[0];
    __syncthreads();
    return out;
}

// ---------------------------------------------------------------- layernorm -> bf16
__global__ __launch_bounds__(256) void layernorm_kernel(
        const float* __restrict__ x, const float* __restrict__ sc,
        const float* __restrict__ bi, unsigned short* __restrict__ out) {
    int row = blockIdx.x;
    const float* xp = x + (size_t)row * ENCD;
    unsigned short* op = out + (size_t)row * ENCD;
    int t = threadIdx.x;
    float v0 = xp[t], v1 = xp[t + 256], v2 = xp[t + 512];
    float mu = block_reduce_sum(v0 + v1 + v2) * (1.f / ENCD);
    float d0 = v0 - mu, d1 = v1 - mu, d2 = v2 - mu;
    float var = block_reduce_sum(d0 * d0 + d1 * d1 + d2 * d2) * (1.f / ENCD);
    float rstd = rsqrtf(var + 1e-5f);
    op[t]       = f2bf(d0 * rstd * sc[t]       + bi[t]);
    op[t + 256] = f2bf(d1 * rstd * sc[t + 256] + bi[t + 256]);
    op[t + 512] = f2bf(d2 * rstd * sc[t + 512] + bi[t + 512]);
}

// ---------------------------------------------------------------- groupnorm -> bf16
__global__ __launch_bounds__(256) void groupnorm_kernel(
        const float* __restrict__ x, const float* __restrict__ sc,
        const float* __restrict__ bi, unsigned short* __restrict__ out) {
    int b = blockIdx.x >> 5, g = blockIdx.x & 31;
    const float* xp = x + (size_t)b * NTOK * CDIM + g * 16;
    unsigned short* op = out + (size_t)b * NTOK * CDIM + g * 16;
    int t = threadIdx.x;

    float s = 0.f;
    for (int idx = t; idx < 4096; idx += 256) {
        int n = idx >> 2, q = idx & 3;
        float4 v = *(const float4*)(xp + n * CDIM + q * 4);
        s += (v.x + v.y) + (v.z + v.w);
    }
    float mu = block_reduce_sum(s) * (1.f / 16384.f);

    float vs = 0.f;
    for (int idx = t; idx < 4096; idx += 256) {
        int n = idx >> 2, q = idx & 3;
        float4 v = *(const float4*)(xp + n * CDIM + q * 4);
        float dx = v.x - mu, dy = v.y - mu, dz = v.z - mu, dw = v.w - mu;
        vs += (dx * dx + dy * dy) + (dz * dz + dw * dw);
    }
    float var = block_reduce_sum(vs) * (1.f / 16384.f);
    float rstd = rsqrtf(var + 1e-5f);

    for (int idx = t; idx < 4096; idx += 256) {
        int n = idx >> 2, q = idx & 3;
        float4 v = *(const float4*)(xp + n * CDIM + q * 4);
        float4 s4 = *(const float4*)(sc + g * 16 + q * 4);
        float4 b4 = *(const float4*)(bi + g * 16 + q * 4);
        ushort4 o;
        o.x = f2bf((v.x - mu) * rstd * s4.x + b4.x);
        o.y = f2bf((v.y - mu) * rstd * s4.y + b4.y);
        o.z = f2bf((v.z - mu) * rstd * s4.z + b4.z);
        o.w = f2bf((v.w - mu) * rstd * s4.w + b4.w);
        *(ushort4*)(op + n * CDIM + q * 4) = o;
    }
}

// ------------------------------------------- transpose + cast: W[K][N] fp32 -> Wt[N+roff][K] bf16
__global__ __launch_bounds__(256) void tcast(
        const float* __restrict__ W, unsigned short* __restrict__ Wt,
        int K, int N, int roff) {
    __shared__ float t[32][33];
    int bn = blockIdx.x * 32, bk = blockIdx.y * 32;
    int lx = threadIdx.x & 31, ly = threadIdx.x >> 5;
    #pragma unroll
    for (int r = 0; r < 4; ++r)
        t[ly + 8 * r][lx] = W[(size_t)(bk + ly + 8 * r) * N + bn + lx];
    __syncthreads();
    #pragma unroll
    for (int r = 0; r < 4; ++r)
        Wt[(size_t)(roff + bn + ly + 8 * r) * K + bk + lx] = f2bf(t[lx][ly + 8 * r]);
}

// ---------------------------------------------------------------- bias concat
__global__ void prep_bias(const float* bq, const float* bk, const float* bv,
                          const float* bak, const float* bav,
                          float* bqkv, float* bakv) {
    int i = blockIdx.x * 256 + threadIdx.x;
    if (i < 512)        bqkv[i] = bq[i];
    else if (i < 1024)  bqkv[i] = bk[i - 512];
    else if (i < 1536)  bqkv[i] = bv[i - 1024];
    else if (i < 2048)  bakv[i - 1536] = bak[i - 1536];
    else if (i < 2560)  bakv[i - 1536] = bav[i - 2048];
}

// ---------------------------------------------------------------- bf16 MFMA GEMM
// D[M,N] = A[M,K](bf16) @ Bt[N,K](bf16)^T + bias.  128x128 block, 4 waves 2x2,
// each wave 64x64 = 4x4 MFMA tiles of 16x16x32.  global_load_lds staging.
// EPI=0: out fp32 row-major [M,ldo], guard row<Mv.
// EPI=1: out-projection epilogue: out[(b*512+row)*1024+n] = acc + bias[row] + resid
template <int EPI>
__global__ __launch_bounds__(256) void mfma_gemm(
        const unsigned short* __restrict__ A, int Mv,
        const unsigned short* __restrict__ Bt,
        const float* __restrict__ bias,
        float* __restrict__ out, int ldo, int K,
        const float* __restrict__ resid) {
    __shared__ alignas(16) unsigned short AsS[128 * 32];
    __shared__ alignas(16) unsigned short BsS[128 * 32];
    int tid = threadIdx.x;
    int wv = tid >> 6, ln = tid & 63;
    int quad = ln >> 4, l16 = ln & 15;
    int wr = wv >> 1, wc = wv & 1;
    int n0 = blockIdx.x * 128, m0 = blockIdx.y * 128;

    floatx4 acc[4][4] = {};

    for (int k0 = 0; k0 < K; k0 += 32) {
        #pragma unroll
        for (int it = 0; it < 2; ++it) {
            int cb = it * 256 + wv * 64;
            int c = cb + ln;
            int r = c >> 2, sg = c & 3;
            int row = m0 + r; if (row > Mv - 1) row = Mv - 1;
            const unsigned short* ga = A + (size_t)row * K + k0 + sg * 8;
            gld16((const void*)ga, (void*)((char*)AsS + cb * 16));
            const unsigned short* gb = Bt + (size_t)(n0 + r) * K + k0 + sg * 8;
            gld16((const void*)gb, (void*)((char*)BsS + cb * 16));
        }
        __syncthreads();
        short8 af[4], bf[4];
        #pragma unroll
        for (int i = 0; i < 4; ++i)
            af[i] = *(const short8*)(AsS + (wr * 64 + i * 16 + l16) * 32 + quad * 8);
        #pragma unroll
        for (int j = 0; j < 4; ++j)
            bf[j] = *(const short8*)(BsS + (wc * 64 + j * 16 + l16) * 32 + quad * 8);
        #pragma unroll
        for (int i = 0; i < 4; ++i)
            #pragma unroll
            for (int j = 0; j < 4; ++j)
                acc[i][j] = __builtin_amdgcn_mfma_f32_16x16x32_bf16(af[i], bf[j], acc[i][j], 0, 0, 0);
        __syncthreads();
    }

    if (EPI == 0) {
        #pragma unroll
        for (int i = 0; i < 4; ++i) {
            int rbase = m0 + wr * 64 + i * 16 + quad * 4;
            #pragma unroll
            for (int j = 0; j < 4; ++j) {
                int col = n0 + wc * 64 + j * 16 + l16;
                float bcol = bias[col];
                #pragma unroll
                for (int r = 0; r < 4; ++r) {
                    int row = rbase + r;
                    if (row < Mv) out[(size_t)row * ldo + col] = acc[i][j][r] + bcol;
                }
            }
        }
    } else {
        // rows are channels c (Mv=512), cols are global tokens n_g (N=2048)
        #pragma unroll
        for (int i = 0; i < 4; ++i) {
            int cbase = m0 + wr * 64 + i * 16 + quad * 4;
            #pragma unroll
            for (int j = 0; j < 4; ++j) {
                int ng = n0 + wc * 64 + j * 16 + l16;
                int b = ng >> 10, n = ng & 1023;
                float4 res = *(const float4*)(resid + ((size_t)(b * 1024 + n)) * 512 + cbase);
                float rr[4] = {res.x, res.y, res.z, res.w};
                #pragma unroll
                for (int r = 0; r < 4; ++r) {
                    int c = cbase + r;
                    out[((size_t)(b * 512 + c)) * 1024 + n] = acc[i][j][r] + bias[c] + rr[r];
                }
            }
        }
    }
}

// ---------------------------------------------------------------- attention
// grid = B*NHEAD*4 blocks, 256 threads; 1 thread = 1 query; chunk-8 online softmax.
// QKV fused fp32 [2048][1536] (Q|K|V), EKV fused fp32 [154][1024] (Kenc|Venc).
// Output AO bf16 [2048][512].
__global__ __launch_bounds__(256) void attn_kernel(
        const float* __restrict__ QKV, const float* __restrict__ EKV,
        unsigned short* __restrict__ AO) {
    __shared__ float Ks[256][8];
    __shared__ float Vs[256][8];
    int bh = blockIdx.x >> 2, qt = blockIdx.x & 3;
    int b = bh >> 6, h = bh & 63;
    int tid = threadIdx.x;
    int n = qt * 256 + tid;
    int coff = h * DHEAD;

    const float* qp = QKV + ((size_t)(b * NTOK + n) * 1536 + coff);
    float4 q0 = *(const float4*)qp;
    float4 q1 = *(const float4*)(qp + 4);
    const float sc = 0.3535533905932738f * 1.4426950408889634f;  // 1/sqrt(8) * log2(e)
    q0.x *= sc; q0.y *= sc; q0.z *= sc; q0.w *= sc;
    q1.x *= sc; q1.y *= sc; q1.z *= sc; q1.w *= sc;

    float m = -INFINITY, l = 0.f;
    float a[8];
    #pragma unroll
    for (int r = 0; r < 8; ++r) a[r] = 0.f;

    for (int j0 = 0; j0 < SKV; j0 += 256) {
        int cnt = SKV - j0; if (cnt > 256) cnt = 256;
        if (tid < cnt) {
            int j = j0 + tid;
            const float* kp; const float* vp;
            if (j < SENC) {
                kp = EKV + (size_t)(b * SENC + j) * 1024 + coff;
                vp = kp + 512;
            } else {
                const float* base = QKV + (size_t)(b * NTOK + (j - SENC)) * 1536 + coff;
                kp = base + 512;
                vp = base + 1024;
            }
            *(float4*)(&Ks[tid][0]) = *(const float4*)kp;
            *(float4*)(&Ks[tid][4]) = *(const float4*)(kp + 4);
            *(float4*)(&Vs[tid][0]) = *(const float4*)vp;
            *(float4*)(&Vs[tid][4]) = *(const float4*)(vp + 4);
        }
        __syncthreads();
        for (int jj = 0; jj < cnt; jj += 8) {
            float s[8];
            #pragma unroll
            for (int t = 0; t < 8; ++t) {
                float4 k0 = *(const float4*)(&Ks[jj + t][0]);
                float4 k1 = *(const float4*)(&Ks[jj + t][4]);
                float d = q0.x * k0.x + q0.y * k0.y + q0.z * k0.z + q0.w * k0.w
                        + q1.x * k1.x + q1.y * k1.y + q1.z * k1.z + q1.w * k1.w;
                s[t] = (jj + t < cnt) ? d : -INFINITY;
            }
            float cm = fmaxf(fmaxf(fmaxf(s[0], s[1]), fmaxf(s[2], s[3])),
                             fmaxf(fmaxf(s[4], s[5]), fmaxf(s[6], s[7])));
            float mn = fmaxf(m, cm);
            float corr = __builtin_amdgcn_exp2f(m - mn);
            float p[8];
            #pragma unroll
            for (int t = 0; t < 8; ++t) p[t] = __builtin_amdgcn_exp2f(s[t] - mn);
            float ps = ((p[0] + p[1]) + (p[2] + p[3])) + ((p[4] + p[5]) + (p[6] + p[7]));
            l = l * corr + ps;
            m = mn;
            #pragma unroll
            for (int r = 0; r < 8; ++r) a[r] *= corr;
            #pragma unroll
            for (int t = 0; t < 8; ++t) {
                float4 v0 = *(const float4*)(&Vs[jj + t][0]);
                float4 v1 = *(const float4*)(&Vs[jj + t][4]);
                a[0] = fmaf(p[t], v0.x, a[0]); a[1] = fmaf(p[t], v0.y, a[1]);
                a[2] = fmaf(p[t], v0.z, a[2]); a[3] = fmaf(p[t], v0.w, a[3]);
                a[4] = fmaf(p[t], v1.x, a[4]); a[5] = fmaf(p[t], v1.y, a[5]);
                a[6] = fmaf(p[t], v1.z, a[6]); a[7] = fmaf(p[t], v1.w, a[7]);
            }
        }
        __syncthreads();
    }
    float inv = 1.f / l;
    union { unsigned short us[8]; uint4 v; } ou;
    #pragma unroll
    for (int r = 0; r < 8; ++r) ou.us[r] = f2bf(a[r] * inv);
    *(uint4*)(AO + ((size_t)(b * NTOK + n) * CDIM + coff)) = ou.v;
}

// ---------------------------------------------------------------- launcher
extern "C" void kernel_launch(void* const* d_in, const int* in_sizes, int n_in,
                              void* d_out, int out_size, void* d_ws, size_t ws_size,
                              hipStream_t stream) {
    const float* x    = (const float*)d_in[0];
    const float* enc  = (const float*)d_in[1];
    const float* gn_s = (const float*)d_in[2];
    const float* gn_b = (const float*)d_in[3];
    const float* ln_s = (const float*)d_in[4];
    const float* ln_b = (const float*)d_in[5];
    const float* Wq  = (const float*)d_in[6];   const float* bq  = (const float*)d_in[7];
    const float* Wk  = (const float*)d_in[8];   const float* bk  = (const float*)d_in[9];
    const float* Wv  = (const float*)d_in[10];  const float* bv  = (const float*)d_in[11];
    const float* Wak = (const float*)d_in[12];  const float* bak = (const float*)d_in[13];
    const float* Wav = (const float*)d_in[14];  const float* bav = (const float*)d_in[15];
    const float* Wo  = (const float*)d_in[16];  const float* bo  = (const float*)d_in[17];
    float* out = (float*)d_out;

    char* p = (char*)d_ws;
    auto alloc = [&](size_t bytes) { char* r = p; p += (bytes + 255) & ~255ULL; return r; };
    unsigned short* hs_bf  = (unsigned short*)alloc((size_t)2048 * 512 * 2);
    unsigned short* enc_bf = (unsigned short*)alloc((size_t)154 * 768 * 2);
    unsigned short* Wqkv_t = (unsigned short*)alloc((size_t)1536 * 512 * 2);
    unsigned short* Wakv_t = (unsigned short*)alloc((size_t)1024 * 768 * 2);
    unsigned short* Wo_t   = (unsigned short*)alloc((size_t)512 * 512 * 2);
    float* bqkv = (float*)alloc(1536 * 4);
    float* bakv = (float*)alloc(1024 * 4);
    float* QKV  = (float*)alloc((size_t)2048 * 1536 * 4);
    float* EKV  = (float*)alloc((size_t)154 * 1024 * 4);
    unsigned short* AO = (unsigned short*)alloc((size_t)2048 * 512 * 2);

    // weight transpose+cast (independent)
    tcast<<<dim3(16, 16), 256, 0, stream>>>(Wq,  Wqkv_t, 512, 512, 0);
    tcast<<<dim3(16, 16), 256, 0, stream>>>(Wk,  Wqkv_t, 512, 512, 512);
    tcast<<<dim3(16, 16), 256, 0, stream>>>(Wv,  Wqkv_t, 512, 512, 1024);
    tcast<<<dim3(16, 24), 256, 0, stream>>>(Wak, Wakv_t, 768, 512, 0);
    tcast<<<dim3(16, 24), 256, 0, stream>>>(Wav, Wakv_t, 768, 512, 512);
    tcast<<<dim3(16, 16), 256, 0, stream>>>(Wo,  Wo_t,   512, 512, 0);
    prep_bias<<<10, 256, 0, stream>>>(bq, bk, bv, bak, bav, bqkv, bakv);

    layernorm_kernel<<<BSZ * SENC, 256, 0, stream>>>(enc, ln_s, ln_b, enc_bf);
    groupnorm_kernel<<<BSZ * 32, 256, 0, stream>>>(x, gn_s, gn_b, hs_bf);

    // QKV: [2048,512] x [512,1536]
    mfma_gemm<0><<<dim3(12, 16), 256, 0, stream>>>(hs_bf, 2048, Wqkv_t, bqkv, QKV, 1536, 512, nullptr);
    // enc K/V: [154,768] x [768,1024]
    mfma_gemm<0><<<dim3(8, 2), 256, 0, stream>>>(enc_bf, 154, Wakv_t, bakv, EKV, 1024, 768, nullptr);

    attn_kernel<<<BSZ * NHEAD * 4, 256, 0, stream>>>(QKV, EKV, AO);

    // out-proj as C^T: A=Wo_t [512,512], Bt=AO [2048,512] -> out [B,C,N] + bias + residual
    mfma_gemm<1><<<dim3(16, 4), 256, 0, stream>>>(Wo_t, 512, AO, bo, out, 1024, 512, x);

    (void)in_sizes; (void)n_in; (void)out_size; (void)ws_size;
}